// Round 1
// baseline (1265.494 us; speedup 1.0000x reference)
//
#include <hip/hip_runtime.h>
#include <cstdint>
#include <cstddef>

#define NROWS 16384
#define KDIM  16384
#define DD    64
#define EPSF  1e-7f
#define MINN  1e-15f
#define MAXN  1e6f
#define KSPLIT 2
#define BK    32

__device__ __forceinline__ float wredsum(float v){
  v += __shfl_xor(v, 1);
  v += __shfl_xor(v, 2);
  v += __shfl_xor(v, 4);
  v += __shfl_xor(v, 8);
  v += __shfl_xor(v, 16);
  v += __shfl_xor(v, 32);
  return v;
}

// ---- tiny: ub = logmap0(proj(expmap0(proj_tan0(b)))) for b1 (wave0) and b2 (wave1)
__global__ __launch_bounds__(128) void k_bias(const float* __restrict__ b1,
                                              const float* __restrict__ b2,
                                              float* __restrict__ ub){
  int w = threadIdx.x >> 6, l = threadIdx.x & 63;
  const float* b = w ? b2 : b1;
  float bv = b[l];
  float tb = l ? bv : 0.f;                 // proj_tan0: zero component 0
  float s  = wredsum(tb*tb);
  float xn = fmaxf(sqrtf(s), MINN);
  float sc = sinhf(xn)/xn;
  float e  = sc*tb;                        // expmap0 tail
  float s2 = wredsum(e*e);
  float x0 = sqrtf(fmaxf(1.f+s2, EPSF));   // proj
  float yn = fmaxf(sqrtf(s2), MINN);
  float th = fmaxf(x0, 1.f+EPSF);
  float u  = l ? acoshf(th)*e/yn : 0.f;    // logmap0
  ub[w*64 + l] = u;
}

// ---- per-row: (pre-chain) -> lx -> lx@W.T -> expmap0/proj -> mobius_add(ub) -> logmap0 -> g
// MODE 0: in = x (raw features): x_hyp = proj(expmap0(proj_tan0(x))), lx = logmap0(x_hyp)
// MODE 1: in = h1 (already on hyperboloid): lx = logmap0(in)
template<int MODE>
__global__ __launch_bounds__(256) void k_linear(const float* __restrict__ in,
                                                const float* __restrict__ W,
                                                const float* __restrict__ ub,
                                                float* __restrict__ g){
  __shared__ float Wt[64*65];              // W transposed, padded: Wt[k*65+j] = W[j,k]
  int tid = threadIdx.x;
  for(int idx = tid; idx < 4096; idx += 256){
    int j = idx >> 6, k = idx & 63;
    Wt[k*65 + j] = W[idx];
  }
  __syncthreads();
  int lane = tid & 63;
  int row  = blockIdx.x*4 + (tid >> 6);
  float v = in[(size_t)row*64 + lane];
  float lx;
  if (MODE == 0){
    float t  = lane ? v : 0.f;
    float s  = wredsum(t*t);
    float tn = fmaxf(sqrtf(s), MINN);
    float sc = sinhf(tn)/tn;
    float e  = sc*t;
    float s2 = wredsum(e*e);
    float x0 = sqrtf(fmaxf(1.f+s2, EPSF));
    float yn = fmaxf(sqrtf(s2), MINN);
    float th = fmaxf(x0, 1.f+EPSF);
    lx = lane ? acoshf(th)*e/yn : 0.f;
  } else {
    float t  = lane ? v : 0.f;
    float s2 = wredsum(t*t);
    float x0 = __shfl(v, 0);
    float yn = fmaxf(sqrtf(s2), MINN);
    float th = fmaxf(x0, 1.f+EPSF);
    lx = lane ? acoshf(th)*t/yn : 0.f;
  }
  // mv[j] = sum_k lx[k] * W[j,k]
  float mv = 0.f;
  #pragma unroll
  for(int k = 0; k < 64; k++){
    mv = fmaf(__shfl(lx, k), Wt[k*65 + lane], mv);
  }
  // expmap0 + proj  -> res = [r0, e]
  float u  = lane ? mv : 0.f;
  float s  = wredsum(u*u);
  float un = fmaxf(sqrtf(s), MINN);
  float sc = sinhf(un)/un;
  float e  = sc*u;
  float s2 = wredsum(e*e);
  float r0 = sqrtf(fmaxf(1.f+s2, EPSF));
  // mobius_add(res, hyp_bias): u_b = ub (precomputed), ptransp0 + proj_tan + expmap + proj
  float ubt   = lane ? ub[lane] : 0.f;
  float yn    = fmaxf(sqrtf(s2), MINN);
  float yhat  = e/yn;
  float alpha = wredsum(yhat*ubt);
  float w     = ubt - alpha*(1.f - r0)*yhat;   // tail of (u - alpha*v); v_tail=(1-x0)*yhat
  float ux    = wredsum(e*w);
  float v0    = ux / fmaxf(r0, EPSF);          // proj_tan component 0
  float md    = wredsum(w*w) - v0*v0;          // mink_dot(v2,v2)
  float normu = fminf(sqrtf(fmaxf(md, EPSF)), MAXN);
  float th2   = fmaxf(normu, MINN);
  float ch    = coshf(th2);
  float shq   = sinhf(th2)/th2;
  float ov    = ch*(lane ? e : r0) + shq*(lane ? w : v0);
  float ot    = lane ? ov : 0.f;
  float s3    = wredsum(ot*ot);
  float o0    = sqrtf(fmaxf(1.f+s3, EPSF));    // proj
  // logmap0 -> g (input to aggregation)
  float yn2 = fmaxf(sqrtf(s3), MINN);
  float th3 = fmaxf(o0, 1.f+EPSF);
  float gv  = lane ? acoshf(th3)*ot/yn2 : 0.f;
  g[(size_t)row*64 + lane] = gv;
}

// ---- split-K matmul: pagg[ks][rows][64] += adj[rows, krange] @ g[krange, 64]; also row sums (FIRST)
template<bool FIRST>
__global__ __launch_bounds__(256) void k_matmul(const float* __restrict__ adj,
                                                const float* __restrict__ g,
                                                float* __restrict__ pagg,
                                                float* __restrict__ prsum){
  __shared__ float adjT[BK][64];
  __shared__ float gt[BK][64];
  __shared__ float rs4[4][64];
  int tid  = threadIdx.x;
  int rb   = blockIdx.x;               // row block (64 rows)
  int ks   = blockIdx.y;               // K split
  int row0 = rb*64;
  size_t k0base = (size_t)ks * (KDIM/KSPLIT);
  int tr = tid >> 4, tc = tid & 15;    // 16x16 threads, each a 4x4 tile
  int lrow = tid & 63;                 // staging: my adj row within block
  int q    = tid >> 6;                 // wave id: which float4 pair of the 32-col chunk
  float acc[4][4] = {{0.f}};
  float rsum = 0.f;
  const float* myrow = adj + (size_t)(row0 + lrow)*KDIM + k0base;
  const int nch = (KDIM/KSPLIT)/BK;
  for(int ch = 0; ch < nch; ch++){
    const float4* rp = (const float4*)(myrow + ch*BK);
    float4 a0 = rp[q];
    float4 a1 = rp[q+4];
    const float4* gp = (const float4*)(g + (k0base + (size_t)ch*BK)*64);
    float4 g0 = gp[tid*2];
    float4 g1 = gp[tid*2 + 1];
    if (FIRST){
      rsum += a0.x+a0.y+a0.z+a0.w + a1.x+a1.y+a1.z+a1.w;
    }
    __syncthreads();
    adjT[q*4+0][lrow]=a0.x; adjT[q*4+1][lrow]=a0.y;
    adjT[q*4+2][lrow]=a0.z; adjT[q*4+3][lrow]=a0.w;
    adjT[16+q*4+0][lrow]=a1.x; adjT[16+q*4+1][lrow]=a1.y;
    adjT[16+q*4+2][lrow]=a1.z; adjT[16+q*4+3][lrow]=a1.w;
    ((float4*)gt)[tid*2]   = g0;
    ((float4*)gt)[tid*2+1] = g1;
    __syncthreads();
    #pragma unroll 8
    for(int kk = 0; kk < BK; kk++){
      float4 av = *(const float4*)&adjT[kk][tr*4];
      float4 bv = *(const float4*)&gt[kk][tc*4];
      acc[0][0]=fmaf(av.x,bv.x,acc[0][0]); acc[0][1]=fmaf(av.x,bv.y,acc[0][1]);
      acc[0][2]=fmaf(av.x,bv.z,acc[0][2]); acc[0][3]=fmaf(av.x,bv.w,acc[0][3]);
      acc[1][0]=fmaf(av.y,bv.x,acc[1][0]); acc[1][1]=fmaf(av.y,bv.y,acc[1][1]);
      acc[1][2]=fmaf(av.y,bv.z,acc[1][2]); acc[1][3]=fmaf(av.y,bv.w,acc[1][3]);
      acc[2][0]=fmaf(av.z,bv.x,acc[2][0]); acc[2][1]=fmaf(av.z,bv.y,acc[2][1]);
      acc[2][2]=fmaf(av.z,bv.z,acc[2][2]); acc[2][3]=fmaf(av.z,bv.w,acc[2][3]);
      acc[3][0]=fmaf(av.w,bv.x,acc[3][0]); acc[3][1]=fmaf(av.w,bv.y,acc[3][1]);
      acc[3][2]=fmaf(av.w,bv.z,acc[3][2]); acc[3][3]=fmaf(av.w,bv.w,acc[3][3]);
    }
  }
  if (FIRST){
    rs4[q][lrow] = rsum;
  }
  __syncthreads();
  if (FIRST && tid < 64){
    float s = rs4[0][tid] + rs4[1][tid] + rs4[2][tid] + rs4[3][tid];
    prsum[(size_t)ks*NROWS + row0 + tid] = s;
  }
  float* outbase = pagg + ((size_t)ks*NROWS + row0)*64;
  #pragma unroll
  for(int rr = 0; rr < 4; rr++){
    float4 o; o.x=acc[rr][0]; o.y=acc[rr][1]; o.z=acc[rr][2]; o.w=acc[rr][3];
    *(float4*)&outbase[(size_t)(tr*4+rr)*64 + tc*4] = o;
  }
}

__global__ __launch_bounds__(256) void k_rinv(const float* __restrict__ prsum,
                                              float* __restrict__ rinv){
  int i = blockIdx.x*256 + threadIdx.x;
  float s = 0.f;
  #pragma unroll
  for(int ks = 0; ks < KSPLIT; ks++) s += prsum[(size_t)ks*NROWS + i];
  rinv[i] = (s != 0.f) ? 1.f/s : 0.f;
}

__global__ __launch_bounds__(256) void k_finalize(const float* __restrict__ pagg,
                                                  const float* __restrict__ rinv,
                                                  float* __restrict__ agg){
  size_t e = (size_t)blockIdx.x*256 + threadIdx.x;
  int i = (int)(e >> 6);
  float s = 0.f;
  #pragma unroll
  for(int ks = 0; ks < KSPLIT; ks++) s += pagg[(size_t)ks*NROWS*64 + e];
  agg[e] = s * rinv[i];
}

// ---- per-row post-aggregation: proj(expmap0(agg)) -> hyp_act -> h
__global__ __launch_bounds__(256) void k_postagg(const float* __restrict__ agg,
                                                 float* __restrict__ h){
  int tid = threadIdx.x; int lane = tid & 63;
  int row = blockIdx.x*4 + (tid >> 6);
  float a  = agg[(size_t)row*64 + lane];
  float at = lane ? a : 0.f;
  float s  = wredsum(at*at);
  float un = fmaxf(sqrtf(s), MINN);
  float sc = sinhf(un)/un;
  float e  = sc*at;
  float s2 = wredsum(e*e);
  float x0 = sqrtf(fmaxf(1.f+s2, EPSF));     // h_agg = [x0, e]
  float yn = fmaxf(sqrtf(s2), MINN);
  float th = fmaxf(x0, 1.f+EPSF);
  float lt = lane ? acoshf(th)*e/yn : 0.f;   // logmap0
  float r  = fmaxf(lt, 0.f);                 // relu (+ proj_tan0 zeroes comp 0)
  float s3 = wredsum(r*r);
  float rn = fmaxf(sqrtf(s3), MINN);
  float sc2= sinhf(rn)/rn;
  float e2 = sc2*r;
  float s4 = wredsum(e2*e2);
  float h0 = sqrtf(fmaxf(1.f+s4, EPSF));     // proj
  h[(size_t)row*64 + lane] = lane ? e2 : h0;
}

extern "C" void kernel_launch(void* const* d_in, const int* in_sizes, int n_in,
                              void* d_out, int out_size, void* d_ws, size_t ws_size,
                              hipStream_t stream){
  const float* x   = (const float*)d_in[0];
  const float* adj = (const float*)d_in[1];
  const float* W1  = (const float*)d_in[2];
  const float* b1  = (const float*)d_in[3];
  const float* W2  = (const float*)d_in[4];
  const float* b2  = (const float*)d_in[5];
  float* out = (float*)d_out;
  float* h1  = out;                    // N*64
  float* h2  = out + (size_t)NROWS*64; // N*64

  float* wsf   = (float*)d_ws;
  float* gbuf  = wsf;                              // N*64   (also reused for agg)
  float* pagg  = gbuf  + (size_t)NROWS*64;         // KSPLIT*N*64
  float* prsum = pagg  + (size_t)KSPLIT*NROWS*64;  // KSPLIT*N
  float* rinv  = prsum + (size_t)KSPLIT*NROWS;     // N
  float* ubs   = rinv  + NROWS;                    // 128

  dim3 gm(NROWS/64, KSPLIT);

  k_bias<<<1, 128, 0, stream>>>(b1, b2, ubs);
  // layer 1
  k_linear<0><<<NROWS/4, 256, 0, stream>>>(x, W1, ubs, gbuf);
  k_matmul<true><<<gm, 256, 0, stream>>>(adj, gbuf, pagg, prsum);
  k_rinv<<<NROWS/256, 256, 0, stream>>>(prsum, rinv);
  k_finalize<<<NROWS*64/256, 256, 0, stream>>>(pagg, rinv, gbuf);   // agg1 -> gbuf
  k_postagg<<<NROWS/4, 256, 0, stream>>>(gbuf, h1);
  // layer 2
  k_linear<1><<<NROWS/4, 256, 0, stream>>>(h1, W2, ubs + 64, gbuf); // g2 -> gbuf
  k_matmul<false><<<gm, 256, 0, stream>>>(adj, gbuf, pagg, prsum);
  k_finalize<<<NROWS*64/256, 256, 0, stream>>>(pagg, rinv, gbuf);   // agg2 -> gbuf
  k_postagg<<<NROWS/4, 256, 0, stream>>>(gbuf, h2);
}

// Round 2
// 603.347 us; speedup vs baseline: 2.0975x; 2.0975x over previous
//
#include <hip/hip_runtime.h>
#include <cstdint>
#include <cstddef>

#define NROWS 16384
#define KDIM  16384
#define EPSF  1e-7f
#define MINN  1e-15f
#define MAXN  1e6f
#define KSPLIT 8
#define BK    32
#define KRANGE (KDIM/KSPLIT)   /* 2048 */
#define NSTEP  (KRANGE/BK)     /* 64 */
#define PGS    1040            /* LDS page stride: 64*16B + 16B pad (bank de-alias) */

typedef __attribute__((ext_vector_type(8))) short short8;
typedef __attribute__((ext_vector_type(4))) float f32x4;
typedef __attribute__((ext_vector_type(4))) unsigned short u16x4;

__device__ __forceinline__ unsigned short f2bf(float f){
  union { float f; unsigned u; } c; c.f = f;
  unsigned u = c.u;
  unsigned r = (u + 0x7FFFu + ((u >> 16) & 1u)) >> 16;   // RNE
  return (unsigned short)r;
}

__device__ __forceinline__ float wredsum(float v){
  v += __shfl_xor(v, 1);
  v += __shfl_xor(v, 2);
  v += __shfl_xor(v, 4);
  v += __shfl_xor(v, 8);
  v += __shfl_xor(v, 16);
  v += __shfl_xor(v, 32);
  return v;
}

// ---- ub = logmap0(proj(expmap0(proj_tan0(b)))) for b1 (wave0) and b2 (wave1)
__global__ __launch_bounds__(128) void k_bias(const float* __restrict__ b1,
                                              const float* __restrict__ b2,
                                              float* __restrict__ ub){
  int w = threadIdx.x >> 6, l = threadIdx.x & 63;
  const float* b = w ? b2 : b1;
  float bv = b[l];
  float tb = l ? bv : 0.f;
  float s  = wredsum(tb*tb);
  float xn = fmaxf(sqrtf(s), MINN);
  float sc = sinhf(xn)/xn;
  float e  = sc*tb;
  float s2 = wredsum(e*e);
  float x0 = sqrtf(fmaxf(1.f+s2, EPSF));
  float yn = fmaxf(sqrtf(s2), MINN);
  float th = fmaxf(x0, 1.f+EPSF);
  float u  = l ? acoshf(th)*e/yn : 0.f;
  ub[w*64 + l] = u;
}

// ---- per-row linear + mobius bias chain -> g (tangent-space input to aggregation)
template<int MODE>
__global__ __launch_bounds__(256) void k_linear(const float* __restrict__ in,
                                                const float* __restrict__ W,
                                                const float* __restrict__ ub,
                                                float* __restrict__ g){
  __shared__ float Wt[64*65];
  int tid = threadIdx.x;
  for(int idx = tid; idx < 4096; idx += 256){
    int j = idx >> 6, k = idx & 63;
    Wt[k*65 + j] = W[idx];
  }
  __syncthreads();
  int lane = tid & 63;
  int row  = blockIdx.x*4 + (tid >> 6);
  float v = in[(size_t)row*64 + lane];
  float lx;
  if (MODE == 0){
    float t  = lane ? v : 0.f;
    float s  = wredsum(t*t);
    float tn = fmaxf(sqrtf(s), MINN);
    float sc = sinhf(tn)/tn;
    float e  = sc*t;
    float s2 = wredsum(e*e);
    float x0 = sqrtf(fmaxf(1.f+s2, EPSF));
    float yn = fmaxf(sqrtf(s2), MINN);
    float th = fmaxf(x0, 1.f+EPSF);
    lx = lane ? acoshf(th)*e/yn : 0.f;
  } else {
    float t  = lane ? v : 0.f;
    float s2 = wredsum(t*t);
    float x0 = __shfl(v, 0);
    float yn = fmaxf(sqrtf(s2), MINN);
    float th = fmaxf(x0, 1.f+EPSF);
    lx = lane ? acoshf(th)*t/yn : 0.f;
  }
  float mv = 0.f;
  #pragma unroll
  for(int k = 0; k < 64; k++){
    mv = fmaf(__shfl(lx, k), Wt[k*65 + lane], mv);
  }
  float u  = lane ? mv : 0.f;
  float s  = wredsum(u*u);
  float un = fmaxf(sqrtf(s), MINN);
  float sc = sinhf(un)/un;
  float e  = sc*u;
  float s2 = wredsum(e*e);
  float r0 = sqrtf(fmaxf(1.f+s2, EPSF));
  float ubt   = lane ? ub[lane] : 0.f;
  float yn    = fmaxf(sqrtf(s2), MINN);
  float yhat  = e/yn;
  float alpha = wredsum(yhat*ubt);
  float w     = ubt - alpha*(1.f - r0)*yhat;
  float ux    = wredsum(e*w);
  float v0    = ux / fmaxf(r0, EPSF);
  float md    = wredsum(w*w) - v0*v0;
  float normu = fminf(sqrtf(fmaxf(md, EPSF)), MAXN);
  float th2   = fmaxf(normu, MINN);
  float ch    = coshf(th2);
  float shq   = sinhf(th2)/th2;
  float ov    = ch*(lane ? e : r0) + shq*(lane ? w : v0);
  float ot    = lane ? ov : 0.f;
  float s3    = wredsum(ot*ot);
  float o0    = sqrtf(fmaxf(1.f+s3, EPSF));
  float yn2 = fmaxf(sqrtf(s3), MINN);
  float th3 = fmaxf(o0, 1.f+EPSF);
  float gv  = lane ? acoshf(th3)*ot/yn2 : 0.f;
  g[(size_t)row*64 + lane] = gv;
}

// ---- MFMA split-K matmul: pagg[ks] = adj[:, krange] @ g[krange, :]; rowsum partials if FIRST
template<bool FIRST>
__global__ __launch_bounds__(256) void k_matmul(const float* __restrict__ adj,
                                                const float* __restrict__ g,
                                                float* __restrict__ pagg,
                                                float* __restrict__ prsum){
  // LDS: k-group subtiled pages: elem(row, k=kg*8+j) at kg*PGS + row*16 + j*2
  __shared__ __align__(16) char As[4*PGS];
  __shared__ __align__(16) char Bs[4*PGS];
  int tid  = threadIdx.x;
  int rb   = blockIdx.x;
  int ks   = blockIdx.y;
  int row0 = rb*64;
  size_t k0 = (size_t)ks * KRANGE;
  int lane = tid & 63, w = tid >> 6;

  // A staging role: thread covers rows r0 and r0+32, k-quad kq (4 floats)
  int r0 = tid >> 3;
  int kq = tid & 7;
  const float* arow0 = adj + (size_t)(row0 + r0)*KDIM + k0 + kq*4;
  const float* arow1 = arow0 + (size_t)32*KDIM;
  char* Awr = As + (kq >> 1)*PGS + r0*16 + (kq & 1)*8;

  // B staging role: thread covers column n, k-group kg (8 k's)
  int nB  = tid & 63;
  int kgB = tid >> 6;
  const float* gcol = g + (k0 + (size_t)kgB*8)*64 + nB;
  char* Bwr = Bs + kgB*PGS + nB*16;

  // fragment read pointers
  const char* Ard  = As + (lane >> 4)*PGS + (w*16 + (lane & 15))*16;
  const char* Brd0 = Bs + (lane >> 4)*PGS + (lane & 15)*16;

  f32x4 acc[4];
  #pragma unroll
  for(int i = 0; i < 4; i++) acc[i] = (f32x4){0.f,0.f,0.f,0.f};
  float rsA = 0.f, rsB = 0.f;

  // prologue loads (step 0)
  float4 a0 = *(const float4*)(arow0);
  float4 a1 = *(const float4*)(arow1);
  float gb[8];
  #pragma unroll
  for(int j = 0; j < 8; j++) gb[j] = gcol[j*64];

  for(int ch = 0; ch < NSTEP; ch++){
    if (FIRST){
      rsA += a0.x + a0.y + a0.z + a0.w;
      rsB += a1.x + a1.y + a1.z + a1.w;
    }
    __syncthreads();                       // previous step's frag reads done
    u16x4 ap0 = { f2bf(a0.x), f2bf(a0.y), f2bf(a0.z), f2bf(a0.w) };
    u16x4 ap1 = { f2bf(a1.x), f2bf(a1.y), f2bf(a1.z), f2bf(a1.w) };
    *(u16x4*)(Awr)       = ap0;            // row r0
    *(u16x4*)(Awr + 512) = ap1;            // row r0+32 (=+32*16B, same page)
    short8 bp;
    #pragma unroll
    for(int j = 0; j < 8; j++) bp[j] = (short)f2bf(gb[j]);
    *(short8*)(Bwr) = bp;
    __syncthreads();                       // staging visible
    short8 af  = *(const short8*)(Ard);
    short8 bf0 = *(const short8*)(Brd0);
    short8 bf1 = *(const short8*)(Brd0 + 256);
    short8 bf2 = *(const short8*)(Brd0 + 512);
    short8 bf3 = *(const short8*)(Brd0 + 768);
    // prefetch next step during MFMA phase (drains at next barrier)
    if (ch + 1 < NSTEP){
      a0 = *(const float4*)(arow0 + (size_t)(ch+1)*BK);
      a1 = *(const float4*)(arow1 + (size_t)(ch+1)*BK);
      #pragma unroll
      for(int j = 0; j < 8; j++) gb[j] = gcol[(size_t)(ch+1)*BK*64 + j*64];
    }
    acc[0] = __builtin_amdgcn_mfma_f32_16x16x32_bf16(af, bf0, acc[0], 0, 0, 0);
    acc[1] = __builtin_amdgcn_mfma_f32_16x16x32_bf16(af, bf1, acc[1], 0, 0, 0);
    acc[2] = __builtin_amdgcn_mfma_f32_16x16x32_bf16(af, bf2, acc[2], 0, 0, 0);
    acc[3] = __builtin_amdgcn_mfma_f32_16x16x32_bf16(af, bf3, acc[3], 0, 0, 0);
  }

  if (FIRST){
    rsA += __shfl_xor(rsA, 1); rsA += __shfl_xor(rsA, 2); rsA += __shfl_xor(rsA, 4);
    rsB += __shfl_xor(rsB, 1); rsB += __shfl_xor(rsB, 2); rsB += __shfl_xor(rsB, 4);
    if (kq == 0){
      prsum[(size_t)ks*NROWS + row0 + r0]      = rsA;
      prsum[(size_t)ks*NROWS + row0 + r0 + 32] = rsB;
    }
  }
  // C write: wave w owns rows [w*16, w*16+16); D: n = lane&15, m = (lane>>4)*4 + r
  float* ob = pagg + ((size_t)ks*NROWS + row0 + w*16)*64;
  #pragma unroll
  for(int nb = 0; nb < 4; nb++){
    int n = nb*16 + (lane & 15);
    #pragma unroll
    for(int r = 0; r < 4; r++){
      int m = (lane >> 4)*4 + r;
      ob[(size_t)m*64 + n] = acc[nb][r];
    }
  }
}

__global__ __launch_bounds__(256) void k_rinv(const float* __restrict__ prsum,
                                              float* __restrict__ rinv){
  int i = blockIdx.x*256 + threadIdx.x;
  float s = 0.f;
  #pragma unroll
  for(int ks = 0; ks < KSPLIT; ks++) s += prsum[(size_t)ks*NROWS + i];
  rinv[i] = (s != 0.f) ? 1.f/s : 0.f;
}

__global__ __launch_bounds__(256) void k_finalize(const float* __restrict__ pagg,
                                                  const float* __restrict__ rinv,
                                                  float* __restrict__ agg){
  size_t e = (size_t)blockIdx.x*256 + threadIdx.x;
  int i = (int)(e >> 6);
  float s = 0.f;
  #pragma unroll
  for(int ks = 0; ks < KSPLIT; ks++) s += pagg[(size_t)ks*NROWS*64 + e];
  agg[e] = s * rinv[i];
}

// ---- per-row post-aggregation: proj(expmap0(agg)) -> hyp_act -> h
__global__ __launch_bounds__(256) void k_postagg(const float* __restrict__ agg,
                                                 float* __restrict__ h){
  int tid = threadIdx.x; int lane = tid & 63;
  int row = blockIdx.x*4 + (tid >> 6);
  float a  = agg[(size_t)row*64 + lane];
  float at = lane ? a : 0.f;
  float s  = wredsum(at*at);
  float un = fmaxf(sqrtf(s), MINN);
  float sc = sinhf(un)/un;
  float e  = sc*at;
  float s2 = wredsum(e*e);
  float x0 = sqrtf(fmaxf(1.f+s2, EPSF));
  float yn = fmaxf(sqrtf(s2), MINN);
  float th = fmaxf(x0, 1.f+EPSF);
  float lt = lane ? acoshf(th)*e/yn : 0.f;
  float r  = fmaxf(lt, 0.f);
  float s3 = wredsum(r*r);
  float rn = fmaxf(sqrtf(s3), MINN);
  float sc2= sinhf(rn)/rn;
  float e2 = sc2*r;
  float s4 = wredsum(e2*e2);
  float h0 = sqrtf(fmaxf(1.f+s4, EPSF));
  h[(size_t)row*64 + lane] = lane ? e2 : h0;
}

extern "C" void kernel_launch(void* const* d_in, const int* in_sizes, int n_in,
                              void* d_out, int out_size, void* d_ws, size_t ws_size,
                              hipStream_t stream){
  const float* x   = (const float*)d_in[0];
  const float* adj = (const float*)d_in[1];
  const float* W1  = (const float*)d_in[2];
  const float* b1  = (const float*)d_in[3];
  const float* W2  = (const float*)d_in[4];
  const float* b2  = (const float*)d_in[5];
  float* out = (float*)d_out;
  float* h1  = out;
  float* h2  = out + (size_t)NROWS*64;

  float* wsf   = (float*)d_ws;
  float* gbuf  = wsf;                              // N*64
  float* pagg  = gbuf  + (size_t)NROWS*64;         // KSPLIT*N*64
  float* prsum = pagg  + (size_t)KSPLIT*NROWS*64;  // KSPLIT*N
  float* rinv  = prsum + (size_t)KSPLIT*NROWS;     // N
  float* ubs   = rinv  + NROWS;                    // 128

  dim3 gm(NROWS/64, KSPLIT);

  k_bias<<<1, 128, 0, stream>>>(b1, b2, ubs);
  // layer 1
  k_linear<0><<<NROWS/4, 256, 0, stream>>>(x, W1, ubs, gbuf);
  k_matmul<true><<<gm, 256, 0, stream>>>(adj, gbuf, pagg, prsum);
  k_rinv<<<NROWS/256, 256, 0, stream>>>(prsum, rinv);
  k_finalize<<<NROWS*64/256, 256, 0, stream>>>(pagg, rinv, gbuf);
  k_postagg<<<NROWS/4, 256, 0, stream>>>(gbuf, h1);
  // layer 2
  k_linear<1><<<NROWS/4, 256, 0, stream>>>(h1, W2, ubs + 64, gbuf);
  k_matmul<false><<<gm, 256, 0, stream>>>(adj, gbuf, pagg, prsum);
  k_finalize<<<NROWS*64/256, 256, 0, stream>>>(pagg, rinv, gbuf);
  k_postagg<<<NROWS/4, 256, 0, stream>>>(gbuf, h2);
}